// Round 1
// baseline (5372.659 us; speedup 1.0000x reference)
//
#include <hip/hip_runtime.h>
#include <math.h>

#define TT 12
#define FF 32
#define HH 64
#define OO 8
#define GG 256   // 4*HH
#define NF 4     // NUM_FUTURE

__device__ __forceinline__ float sigmoidf_(float x){ return 1.f/(1.f+expf(-x)); }

// ---- degree ----
__global__ void deg_kernel(const int* __restrict__ dst, float* __restrict__ deg, int E){
  int e = blockIdx.x*blockDim.x + threadIdx.x;
  if (e < E) atomicAdd(&deg[dst[e]], 1.0f);
}
__global__ void invd_kernel(float* deg, int N){
  int i = blockIdx.x*blockDim.x + threadIdx.x;
  if (i < N) deg[i] = 1.f / fmaxf(deg[i], 1.f);
}

// ---- SAGE neighbor aggregation over all T (32 features) ----
__global__ void sage_scatter(const float* __restrict__ x, const int* __restrict__ src,
                             const int* __restrict__ dst, const float* __restrict__ ew,
                             float* __restrict__ agg, int E, int N){
  int idx = blockIdx.x*blockDim.x + threadIdx.x;
  if (idx >= E*FF) return;
  int e = idx >> 5, f = idx & (FF-1);
  int s = src[e]*FF + f, d = dst[e]*FF + f;
  float w = ew[e];
  #pragma unroll
  for (int t = 0; t < TT; ++t)
    atomicAdd(&agg[(size_t)t*N*FF + d], x[(size_t)t*N*FF + s] * w);
}

// ---- SAGE linear: emb = (agg*invd)@Wr + x@Wroot + b ; xr = relu(emb) ----
__global__ __launch_bounds__(256) void sage_gemm(
    const float* __restrict__ x, const float* __restrict__ agg,
    const float* __restrict__ invd,
    const float* __restrict__ Wr, const float* __restrict__ Wroot,
    const float* __restrict__ b,
    float* __restrict__ emb, float* __restrict__ xr, int N){
  __shared__ float sWr[FF*HH], sWroot[FF*HH];
  for (int i = threadIdx.x; i < FF*HH; i += 256){ sWr[i] = Wr[i]; sWroot[i] = Wroot[i]; }
  __syncthreads();
  int idx = blockIdx.x*256 + threadIdx.x;      // flat (row, h)
  int row = idx >> 6, hh = idx & (HH-1);
  if (row >= TT*N) return;
  int n = row % N;
  const float* xv = x  + (size_t)row*FF;
  const float* av = agg + (size_t)row*FF;
  float id = invd[n];
  float acc = b[hh];
  #pragma unroll
  for (int k = 0; k < FF; ++k)
    acc += av[k]*id*sWr[k*HH+hh] + xv[k]*sWroot[k*HH+hh];
  emb[(size_t)row*HH + hh] = acc;
  xr[(size_t)row*HH + hh]  = fmaxf(acc, 0.f);
}

// ---- xr neighbor aggregation over all T (64 features) ----
__global__ void xragg_scatter(const float* __restrict__ xr, const int* __restrict__ src,
                              const int* __restrict__ dst, const float* __restrict__ ew,
                              float* __restrict__ agg, int E, int N){
  int idx = blockIdx.x*blockDim.x + threadIdx.x;
  if (idx >= E*HH) return;
  int e = idx >> 6, f = idx & (HH-1);
  int s = src[e]*HH + f, d = dst[e]*HH + f;
  float w = ew[e];
  #pragma unroll
  for (int t = 0; t < TT; ++t)
    atomicAdd(&agg[(size_t)t*N*HH + d], xr[(size_t)t*N*HH + s] * w);
}

// ---- per-step h aggregation (64 features) ----
__global__ void hscatter(const float* __restrict__ h, const int* __restrict__ src,
                         const int* __restrict__ dst, const float* __restrict__ ew,
                         float* __restrict__ hagg, int E){
  int idx = blockIdx.x*blockDim.x + threadIdx.x;
  if (idx >= E*HH) return;
  int e = idx >> 6, f = idx & (HH-1);
  atomicAdd(&hagg[dst[e]*HH + f], h[src[e]*HH + f] * ew[e]);
}

// ---- fused gates GEMM + LSTM cell, 16 rows per block ----
// gates = [xr_agg*id, h_agg*id, xr, h] @ [Wr ; Wroot] + b  (K=256, J=256)
__global__ __launch_bounds__(256) void lstm_step(
    const float* __restrict__ xr_t, const float* __restrict__ xragg_t,
    const float* __restrict__ h_agg, float* __restrict__ h, float* __restrict__ c,
    const float* __restrict__ invd,
    const float* __restrict__ Wr, const float* __restrict__ Wroot,
    const float* __restrict__ b,
    float* __restrict__ h2_store, int N){
  __shared__ float lds[16][GG];
  int base = blockIdx.x * 16;
  int tid  = threadIdx.x;
  // stage inputs: row-major [16][K=256]
  for (int r = 0; r < 16; ++r){
    int n = base + r;
    float id = invd[n];
    int k = tid;
    float v;
    if      (k < 64)  v = xragg_t[(size_t)n*HH + k] * id;
    else if (k < 128) v = h_agg  [(size_t)n*HH + (k-64)] * id;
    else if (k < 192) v = xr_t   [(size_t)n*HH + (k-128)];
    else              v = h      [(size_t)n*HH + (k-192)];
    lds[r][k] = v;
  }
  __syncthreads();
  int j = tid;
  float acc[16];
  #pragma unroll
  for (int r = 0; r < 16; ++r) acc[r] = b[j];
  #pragma unroll 4
  for (int k = 0; k < 128; ++k){
    float wv = Wr[k*GG + j];
    #pragma unroll
    for (int r = 0; r < 16; ++r) acc[r] += lds[r][k]*wv;
  }
  #pragma unroll 4
  for (int k = 0; k < 128; ++k){
    float wv = Wroot[k*GG + j];
    #pragma unroll
    for (int r = 0; r < 16; ++r) acc[r] += lds[r][128+k]*wv;
  }
  __syncthreads();
  #pragma unroll
  for (int r = 0; r < 16; ++r) lds[r][j] = acc[r];   // gates
  __syncthreads();
  // cell update: 4 groups of 64 lanes
  int g = tid >> 6, hx = tid & 63;
  for (int r = g; r < 16; r += 4){
    int n = base + r;
    float gi = lds[r][hx], gf = lds[r][64+hx], gg = lds[r][128+hx], go = lds[r][192+hx];
    float cn = sigmoidf_(gf)*c[(size_t)n*HH+hx] + sigmoidf_(gi)*tanhf(gg);
    float hn = sigmoidf_(go)*tanhf(cn);
    c[(size_t)n*HH+hx] = cn;
    h[(size_t)n*HH+hx] = hn;
    if (h2_store) h2_store[(size_t)n*HH+hx] = hn;
  }
}

// ---- output head: out = [xr[8+tt], h2[tt]] @ W_out + b_out ----
__global__ void out_gemm(const float* __restrict__ xr8, const float* __restrict__ h2s,
                         const float* __restrict__ Wout, const float* __restrict__ bout,
                         float* __restrict__ out, int N){
  int idx = blockIdx.x*blockDim.x + threadIdx.x;
  if (idx >= NF*N*OO) return;
  int o = idx & (OO-1);
  int row = idx >> 3;                     // tt*N + n
  const float* xv = xr8 + (size_t)row*HH;
  const float* hv = h2s + (size_t)row*HH;
  float acc = bout[o];
  #pragma unroll
  for (int k = 0; k < HH; ++k)
    acc += xv[k]*Wout[k*OO+o] + hv[k]*Wout[(HH+k)*OO+o];
  out[idx] = acc;
}

__global__ void copyk(const float* __restrict__ s, float* __restrict__ d, int n){
  int i = blockIdx.x*blockDim.x + threadIdx.x;
  if (i < n) d[i] = s[i];
}

extern "C" void kernel_launch(void* const* d_in, const int* in_sizes, int n_in,
                              void* d_out, int out_size, void* d_ws, size_t ws_size,
                              hipStream_t stream){
  const float* x      = (const float*)d_in[0];
  const int*   ei     = (const int*)  d_in[1];
  const float* ew     = (const float*)d_in[2];
  const float* sWr    = (const float*)d_in[3];
  const float* sWroot = (const float*)d_in[4];
  const float* sb     = (const float*)d_in[5];
  const float* l1Wr   = (const float*)d_in[6];
  const float* l1Wroot= (const float*)d_in[7];
  const float* l1b    = (const float*)d_in[8];
  const float* l2Wr   = (const float*)d_in[9];
  const float* l2Wroot= (const float*)d_in[10];
  const float* l2b    = (const float*)d_in[11];
  const float* Wout   = (const float*)d_in[12];
  const float* bout   = (const float*)d_in[13];

  const int E = in_sizes[2];
  const int N = in_sizes[0] / (TT*FF);
  const int* src = ei;
  const int* dst = ei + E;

  float* out0   = (float*)d_out;              // [4,N,8]
  float* c2out  = out0 + (size_t)NF*N*OO;     // [N,64]
  float* embout = c2out + (size_t)N*HH;       // [12,N,64]

  float* w = (float*)d_ws;
  float* xr     = w;  w += (size_t)TT*N*HH;
  float* xr_agg = w;  w += (size_t)TT*N*HH;
  float* agg_x  = w;  w += (size_t)TT*N*FF;
  float* hbuf   = w;  w += (size_t)N*HH;
  float* cbuf   = w;  w += (size_t)N*HH;      // adjacent to hbuf -> one memset
  float* h_agg  = w;  w += (size_t)N*HH;
  float* h2s    = w;  w += (size_t)NF*N*HH;
  float* invd   = w;  w += N;

  // zero accumulators
  hipMemsetAsync(invd,   0, (size_t)N*4, stream);
  hipMemsetAsync(agg_x,  0, (size_t)TT*N*FF*4, stream);
  hipMemsetAsync(xr_agg, 0, (size_t)TT*N*HH*4, stream);
  hipMemsetAsync(hbuf,   0, (size_t)2*N*HH*4, stream);   // h and c

  deg_kernel<<<(E+255)/256, 256, 0, stream>>>(dst, invd, E);
  invd_kernel<<<(N+255)/256, 256, 0, stream>>>(invd, N);

  sage_scatter<<<((size_t)E*FF+255)/256, 256, 0, stream>>>(x, src, dst, ew, agg_x, E, N);
  sage_gemm<<<((size_t)TT*N*HH+255)/256, 256, 0, stream>>>(x, agg_x, invd, sWr, sWroot, sb,
                                                            embout, xr, N);
  xragg_scatter<<<((size_t)E*HH+255)/256, 256, 0, stream>>>(xr, src, dst, ew, xr_agg, E, N);

  const int stepBlocks = N/16;           // N=20000 -> 1250
  // LSTM1: 12 steps
  for (int t = 0; t < TT; ++t){
    hipMemsetAsync(h_agg, 0, (size_t)N*HH*4, stream);
    hscatter<<<((size_t)E*HH+255)/256, 256, 0, stream>>>(hbuf, src, dst, ew, h_agg, E);
    lstm_step<<<stepBlocks, 256, 0, stream>>>(xr + (size_t)t*N*HH, xr_agg + (size_t)t*N*HH,
                                              h_agg, hbuf, cbuf, invd,
                                              l1Wr, l1Wroot, l1b, nullptr, N);
  }
  // LSTM2: continues from (h1[-1], c1); h2 stored for t>=8
  for (int t = 0; t < TT; ++t){
    hipMemsetAsync(h_agg, 0, (size_t)N*HH*4, stream);
    hscatter<<<((size_t)E*HH+255)/256, 256, 0, stream>>>(hbuf, src, dst, ew, h_agg, E);
    float* store = (t >= TT-NF) ? (h2s + (size_t)(t-(TT-NF))*N*HH) : nullptr;
    lstm_step<<<stepBlocks, 256, 0, stream>>>(xr + (size_t)t*N*HH, xr_agg + (size_t)t*N*HH,
                                              h_agg, hbuf, cbuf, invd,
                                              l2Wr, l2Wroot, l2b, store, N);
  }

  out_gemm<<<((size_t)NF*N*OO+255)/256, 256, 0, stream>>>(xr + (size_t)(TT-NF)*N*HH, h2s,
                                                          Wout, bout, out0, N);
  copyk<<<((size_t)N*HH+255)/256, 256, 0, stream>>>(cbuf, c2out, N*HH);
}

// Round 2
// 4724.482 us; speedup vs baseline: 1.1372x; 1.1372x over previous
//
#include <hip/hip_runtime.h>
#include <math.h>

#define TT 12
#define FF 32
#define HH 64
#define OO 8
#define GG 256   // 4*HH
#define NF 4     // NUM_FUTURE

__device__ __forceinline__ float sigmoidf_(float x){ return 1.f/(1.f+expf(-x)); }

// ================= CSR build =================
__global__ void hist_kernel(const int* __restrict__ dst, int* __restrict__ cnt, int E){
  int e = blockIdx.x*blockDim.x + threadIdx.x;
  if (e < E) atomicAdd(&cnt[dst[e]], 1);
}

// one-block exclusive scan over N counts -> ptr[N+1]; also invd = 1/max(cnt,1)
__global__ __launch_bounds__(1024) void scan_kernel(const int* __restrict__ cnt,
                                                    int* __restrict__ ptr,
                                                    float* __restrict__ invd, int N){
  __shared__ int buf[1024];
  __shared__ int carry;
  if (threadIdx.x == 0) carry = 0;
  __syncthreads();
  for (int base = 0; base < N; base += 1024){
    int i = base + threadIdx.x;
    int v = (i < N) ? cnt[i] : 0;
    buf[threadIdx.x] = v;
    __syncthreads();
    for (int off = 1; off < 1024; off <<= 1){
      int t = (threadIdx.x >= off) ? buf[threadIdx.x - off] : 0;
      __syncthreads();
      buf[threadIdx.x] += t;
      __syncthreads();
    }
    int incl = buf[threadIdx.x];
    if (i < N){
      ptr[i] = carry + incl - v;
      invd[i] = 1.f / fmaxf((float)v, 1.f);
    }
    __syncthreads();
    if (threadIdx.x == 1023){
      carry += incl;
      if (base + 1024 >= N) ptr[N] = carry;
    }
    __syncthreads();
  }
}

__global__ void fill_kernel(const int* __restrict__ src, const int* __restrict__ dst,
                            const float* __restrict__ ew, const int* __restrict__ ptr,
                            int* __restrict__ fill, int* __restrict__ csr_src,
                            float* __restrict__ csr_w, int E){
  int e = blockIdx.x*blockDim.x + threadIdx.x;
  if (e >= E) return;
  int d = dst[e];
  int pos = ptr[d] + atomicAdd(&fill[d], 1);
  csr_src[pos] = src[e];
  csr_w[pos]   = ew[e];
}

// ================= SAGE aggregation (gather, 32 feats, 12 t) =================
// one wave per node; lane&31 = feature, lane>>5 = t parity
__global__ __launch_bounds__(256) void sage_gather(
    const float* __restrict__ x, const int* __restrict__ ptr,
    const int* __restrict__ csr_src, const float* __restrict__ csr_w,
    const float* __restrict__ invd, float* __restrict__ aggx, int N){
  int wave = threadIdx.x >> 6, lane = threadIdx.x & 63;
  int f = lane & 31, tp = lane >> 5;
  int n = blockIdx.x*4 + wave;
  if (n >= N) return;
  int beg = ptr[n], end = ptr[n+1];
  float id = invd[n];
  for (int th = 0; th < TT/2; ++th){
    int t = th*2 + tp;
    const float* bx = x + (size_t)t*N*FF;
    float acc = 0.f;
    for (int e = beg; e < end; ++e)
      acc += bx[(size_t)csr_src[e]*FF + f] * csr_w[e];
    aggx[(size_t)t*N*FF + (size_t)n*FF + f] = acc * id;   // pre-normalized
  }
}

// ================= SAGE linear: emb = agg@Wr + x@Wroot + b ; xr = relu =====
__global__ __launch_bounds__(256) void sage_gemm(
    const float* __restrict__ x, const float* __restrict__ agg,
    const float* __restrict__ Wr, const float* __restrict__ Wroot,
    const float* __restrict__ b,
    float* __restrict__ emb, float* __restrict__ xr, int N){
  __shared__ float sWr[FF*HH], sWroot[FF*HH];
  for (int i = threadIdx.x; i < FF*HH; i += 256){ sWr[i] = Wr[i]; sWroot[i] = Wroot[i]; }
  __syncthreads();
  int idx = blockIdx.x*256 + threadIdx.x;
  int row = idx >> 6, hh = idx & (HH-1);
  if (row >= TT*N) return;
  const float* xv = x   + (size_t)row*FF;
  const float* av = agg + (size_t)row*FF;
  float acc = b[hh];
  #pragma unroll
  for (int k = 0; k < FF; ++k)
    acc += av[k]*sWr[k*HH+hh] + xv[k]*sWroot[k*HH+hh];
  emb[(size_t)row*HH + hh] = acc;
  xr[(size_t)row*HH + hh]  = fmaxf(acc, 0.f);
}

// ================= xr aggregation (gather, 64 feats, 12 t) =================
__global__ __launch_bounds__(256) void xr_gather(
    const float* __restrict__ xr, const int* __restrict__ ptr,
    const int* __restrict__ csr_src, const float* __restrict__ csr_w,
    const float* __restrict__ invd, float* __restrict__ xr_agg, int N){
  int wave = threadIdx.x >> 6, lane = threadIdx.x & 63;
  int n = blockIdx.x*4 + wave;
  if (n >= N) return;
  int beg = ptr[n], end = ptr[n+1];
  float id = invd[n];
  for (int t = 0; t < TT; ++t){
    const float* bx = xr + (size_t)t*N*HH;
    float acc = 0.f;
    for (int e = beg; e < end; ++e)
      acc += bx[(size_t)csr_src[e]*HH + lane] * csr_w[e];
    xr_agg[(size_t)t*N*HH + (size_t)n*HH + lane] = acc * id;  // pre-normalized
  }
}

// ============ fused: h-gather + gates GEMM + LSTM cell, 16 nodes/block ======
// inp = [xr_agg(pre-norm), h_agg*invd, xr, h] ; gates = inp @ [Wr;Wroot] + b
__global__ __launch_bounds__(256) void lstm_step(
    const float* __restrict__ xr_t, const float* __restrict__ xragg_t,
    const float* __restrict__ h_prev, float* __restrict__ h_next,
    float* __restrict__ c, const float* __restrict__ invd,
    const int* __restrict__ ptr, const int* __restrict__ csr_src,
    const float* __restrict__ csr_w,
    const float* __restrict__ Wr, const float* __restrict__ Wroot,
    const float* __restrict__ b,
    float* __restrict__ h2_store, int N){
  __shared__ float lds[16][GG];
  int tid = threadIdx.x, wave = tid >> 6, lane = tid & 63;
  int base = blockIdx.x * 16;

  // ---- Phase A: gather h_agg + stage inputs (wave w owns rows 4w..4w+3) ----
  for (int r4 = 0; r4 < 4; ++r4){
    int r = wave*4 + r4;
    int n = base + r;
    if (n < N){
      float id = invd[n];
      int beg = ptr[n], end = ptr[n+1];
      float acc = 0.f;
      for (int e = beg; e < end; ++e)
        acc += h_prev[(size_t)csr_src[e]*HH + lane] * csr_w[e];
      lds[r][ 64+lane] = acc * id;
      lds[r][    lane] = xragg_t[(size_t)n*HH + lane];
      lds[r][128+lane] = xr_t   [(size_t)n*HH + lane];
      lds[r][192+lane] = h_prev [(size_t)n*HH + lane];
    } else {
      lds[r][lane] = lds[r][64+lane] = lds[r][128+lane] = lds[r][192+lane] = 0.f;
    }
  }
  __syncthreads();

  // ---- Phase B: GEMM, 4 rows x 4 cols per thread ----
  int rg = wave;              // rows rg*4 .. rg*4+3
  int j0 = lane * 4;          // cols j0 .. j0+3
  float acc[4][4];
  {
    float4 bv = *(const float4*)&b[j0];
    #pragma unroll
    for (int r = 0; r < 4; ++r){
      acc[r][0]=bv.x; acc[r][1]=bv.y; acc[r][2]=bv.z; acc[r][3]=bv.w;
    }
  }
  #pragma unroll 4
  for (int k = 0; k < 128; k += 4){
    float4 w0 = *(const float4*)&Wr[(size_t)(k+0)*GG + j0];
    float4 w1 = *(const float4*)&Wr[(size_t)(k+1)*GG + j0];
    float4 w2 = *(const float4*)&Wr[(size_t)(k+2)*GG + j0];
    float4 w3 = *(const float4*)&Wr[(size_t)(k+3)*GG + j0];
    #pragma unroll
    for (int r = 0; r < 4; ++r){
      float4 a = *(const float4*)&lds[rg*4+r][k];
      acc[r][0] += a.x*w0.x + a.y*w1.x + a.z*w2.x + a.w*w3.x;
      acc[r][1] += a.x*w0.y + a.y*w1.y + a.z*w2.y + a.w*w3.y;
      acc[r][2] += a.x*w0.z + a.y*w1.z + a.z*w2.z + a.w*w3.z;
      acc[r][3] += a.x*w0.w + a.y*w1.w + a.z*w2.w + a.w*w3.w;
    }
  }
  #pragma unroll 4
  for (int k = 0; k < 128; k += 4){
    float4 w0 = *(const float4*)&Wroot[(size_t)(k+0)*GG + j0];
    float4 w1 = *(const float4*)&Wroot[(size_t)(k+1)*GG + j0];
    float4 w2 = *(const float4*)&Wroot[(size_t)(k+2)*GG + j0];
    float4 w3 = *(const float4*)&Wroot[(size_t)(k+3)*GG + j0];
    #pragma unroll
    for (int r = 0; r < 4; ++r){
      float4 a = *(const float4*)&lds[rg*4+r][128+k];
      acc[r][0] += a.x*w0.x + a.y*w1.x + a.z*w2.x + a.w*w3.x;
      acc[r][1] += a.x*w0.y + a.y*w1.y + a.z*w2.y + a.w*w3.y;
      acc[r][2] += a.x*w0.z + a.y*w1.z + a.z*w2.z + a.w*w3.z;
      acc[r][3] += a.x*w0.w + a.y*w1.w + a.z*w2.w + a.w*w3.w;
    }
  }
  __syncthreads();                      // done reading A-tile
  #pragma unroll
  for (int r = 0; r < 4; ++r){
    float4 g4; g4.x=acc[r][0]; g4.y=acc[r][1]; g4.z=acc[r][2]; g4.w=acc[r][3];
    *(float4*)&lds[rg*4+r][j0] = g4;    // gates
  }
  __syncthreads();

  // ---- Phase C: cell update ----
  int g = wave, hx = lane;
  for (int r = g; r < 16; r += 4){
    int n = base + r;
    if (n >= N) continue;
    float gi = lds[r][hx], gf = lds[r][64+hx], gg2 = lds[r][128+hx], go = lds[r][192+hx];
    float cn = sigmoidf_(gf)*c[(size_t)n*HH+hx] + sigmoidf_(gi)*tanhf(gg2);
    float hn = sigmoidf_(go)*tanhf(cn);
    c[(size_t)n*HH+hx] = cn;
    h_next[(size_t)n*HH+hx] = hn;
    if (h2_store) h2_store[(size_t)n*HH+hx] = hn;
  }
}

// ================= output head =================
__global__ void out_gemm(const float* __restrict__ xr8, const float* __restrict__ h2s,
                         const float* __restrict__ Wout, const float* __restrict__ bout,
                         float* __restrict__ out, int N){
  int idx = blockIdx.x*blockDim.x + threadIdx.x;
  if (idx >= NF*N*OO) return;
  int o = idx & (OO-1);
  int row = idx >> 3;                     // tt*N + n
  const float* xv = xr8 + (size_t)row*HH;
  const float* hv = h2s + (size_t)row*HH;
  float acc = bout[o];
  #pragma unroll
  for (int k = 0; k < HH; ++k)
    acc += xv[k]*Wout[k*OO+o] + hv[k]*Wout[(HH+k)*OO+o];
  out[idx] = acc;
}

__global__ void copyk(const float* __restrict__ s, float* __restrict__ d, int n){
  int i = blockIdx.x*blockDim.x + threadIdx.x;
  if (i < n) d[i] = s[i];
}

extern "C" void kernel_launch(void* const* d_in, const int* in_sizes, int n_in,
                              void* d_out, int out_size, void* d_ws, size_t ws_size,
                              hipStream_t stream){
  const float* x      = (const float*)d_in[0];
  const int*   ei     = (const int*)  d_in[1];
  const float* ew     = (const float*)d_in[2];
  const float* sWr    = (const float*)d_in[3];
  const float* sWroot = (const float*)d_in[4];
  const float* sb     = (const float*)d_in[5];
  const float* l1Wr   = (const float*)d_in[6];
  const float* l1Wroot= (const float*)d_in[7];
  const float* l1b    = (const float*)d_in[8];
  const float* l2Wr   = (const float*)d_in[9];
  const float* l2Wroot= (const float*)d_in[10];
  const float* l2b    = (const float*)d_in[11];
  const float* Wout   = (const float*)d_in[12];
  const float* bout   = (const float*)d_in[13];

  const int E = in_sizes[2];
  const int N = in_sizes[0] / (TT*FF);
  const int* src = ei;
  const int* dst = ei + E;

  float* out0   = (float*)d_out;              // [4,N,8]
  float* c2out  = out0 + (size_t)NF*N*OO;     // [N,64]
  float* embout = c2out + (size_t)N*HH;       // [12,N,64]

  float* w = (float*)d_ws;
  float* xr     = w;  w += (size_t)TT*N*HH;
  float* xr_agg = w;  w += (size_t)TT*N*HH;
  float* agg_x  = xr_agg;                     // alias: dead before xr_agg written
  float* hA     = w;  w += (size_t)N*HH;
  float* hB     = w;  w += (size_t)N*HH;
  float* cbuf   = w;  w += (size_t)N*HH;
  float* h2s    = w;  w += (size_t)NF*N*HH;
  float* invd   = w;  w += N;
  int*   cnt    = (int*)w;  w += N;
  int*   fill   = (int*)w;  w += N;
  int*   ptr    = (int*)w;  w += (N+1);
  int*   csr_src= (int*)w;  w += E;
  float* csr_w  = w;  w += E;

  hipMemsetAsync(cnt,  0, (size_t)N*4, stream);
  hipMemsetAsync(fill, 0, (size_t)N*4, stream);
  hipMemsetAsync(hA,   0, (size_t)N*HH*4, stream);  // h0
  hipMemsetAsync(cbuf, 0, (size_t)N*HH*4, stream);  // c0

  hist_kernel<<<(E+255)/256, 256, 0, stream>>>(dst, cnt, E);
  scan_kernel<<<1, 1024, 0, stream>>>(cnt, ptr, invd, N);
  fill_kernel<<<(E+255)/256, 256, 0, stream>>>(src, dst, ew, ptr, fill, csr_src, csr_w, E);

  sage_gather<<<(N+3)/4, 256, 0, stream>>>(x, ptr, csr_src, csr_w, invd, agg_x, N);
  sage_gemm<<<((size_t)TT*N*HH+255)/256, 256, 0, stream>>>(x, agg_x, sWr, sWroot, sb,
                                                           embout, xr, N);
  xr_gather<<<(N+3)/4, 256, 0, stream>>>(xr, ptr, csr_src, csr_w, invd, xr_agg, N);

  const int stepBlocks = (N+15)/16;
  float* hp = hA; float* hn = hB;
  // LSTM1
  for (int t = 0; t < TT; ++t){
    lstm_step<<<stepBlocks, 256, 0, stream>>>(xr + (size_t)t*N*HH, xr_agg + (size_t)t*N*HH,
                                              hp, hn, cbuf, invd, ptr, csr_src, csr_w,
                                              l1Wr, l1Wroot, l1b, nullptr, N);
    float* tmp = hp; hp = hn; hn = tmp;
  }
  // LSTM2 (continues from h1[-1], c1)
  for (int t = 0; t < TT; ++t){
    float* store = (t >= TT-NF) ? (h2s + (size_t)(t-(TT-NF))*N*HH) : nullptr;
    lstm_step<<<stepBlocks, 256, 0, stream>>>(xr + (size_t)t*N*HH, xr_agg + (size_t)t*N*HH,
                                              hp, hn, cbuf, invd, ptr, csr_src, csr_w,
                                              l2Wr, l2Wroot, l2b, store, N);
    float* tmp = hp; hp = hn; hn = tmp;
  }

  out_gemm<<<((size_t)NF*N*OO+255)/256, 256, 0, stream>>>(xr + (size_t)(TT-NF)*N*HH, h2s,
                                                          Wout, bout, out0, N);
  copyk<<<((size_t)N*HH+255)/256, 256, 0, stream>>>(cbuf, c2out, N*HH);
}

// Round 3
// 3217.942 us; speedup vs baseline: 1.6696x; 1.4682x over previous
//
#include <hip/hip_runtime.h>
#include <math.h>

#define TT 12
#define FF 32
#define HH 64
#define OO 8
#define GG 256   // 4*HH
#define NF 4     // NUM_FUTURE

__device__ __forceinline__ float sigmoidf_(float x){ return 1.f/(1.f+expf(-x)); }

// ================= CSR build =================
__global__ void hist_kernel(const int* __restrict__ dst, int* __restrict__ cnt, int E){
  int e = blockIdx.x*blockDim.x + threadIdx.x;
  if (e < E) atomicAdd(&cnt[dst[e]], 1);
}

// one-block exclusive scan over N counts -> ptr[N+1]; also invd = 1/max(cnt,1)
__global__ __launch_bounds__(1024) void scan_kernel(const int* __restrict__ cnt,
                                                    int* __restrict__ ptr,
                                                    float* __restrict__ invd, int N){
  __shared__ int buf[1024];
  __shared__ int carry;
  if (threadIdx.x == 0) carry = 0;
  __syncthreads();
  for (int base = 0; base < N; base += 1024){
    int i = base + threadIdx.x;
    int v = (i < N) ? cnt[i] : 0;
    buf[threadIdx.x] = v;
    __syncthreads();
    for (int off = 1; off < 1024; off <<= 1){
      int t = (threadIdx.x >= off) ? buf[threadIdx.x - off] : 0;
      __syncthreads();
      buf[threadIdx.x] += t;
      __syncthreads();
    }
    int incl = buf[threadIdx.x];
    if (i < N){
      ptr[i] = carry + incl - v;
      invd[i] = 1.f / fmaxf((float)v, 1.f);
    }
    __syncthreads();
    if (threadIdx.x == 1023){
      carry += incl;
      if (base + 1024 >= N) ptr[N] = carry;
    }
    __syncthreads();
  }
}

__global__ void fill_kernel(const int* __restrict__ src, const int* __restrict__ dst,
                            const float* __restrict__ ew, const int* __restrict__ ptr,
                            int* __restrict__ fill, int* __restrict__ csr_src,
                            float* __restrict__ csr_w, int E){
  int e = blockIdx.x*blockDim.x + threadIdx.x;
  if (e >= E) return;
  int d = dst[e];
  int pos = ptr[d] + atomicAdd(&fill[d], 1);
  csr_src[pos] = src[e];
  csr_w[pos]   = ew[e];
}

// ========== SAGE aggregation: t-inner, 6 accumulators per lane ==========
// lane&31 = feature, lane>>5 = t parity; 12 independent loads in flight / edge
__global__ __launch_bounds__(256) void sage_gather(
    const float* __restrict__ x, const int* __restrict__ ptr,
    const int* __restrict__ csr_src, const float* __restrict__ csr_w,
    const float* __restrict__ invd, float* __restrict__ aggx, int N){
  int wave = threadIdx.x >> 6, lane = threadIdx.x & 63;
  int f = lane & 31, tp = lane >> 5;
  int n = blockIdx.x*4 + wave;
  if (n >= N) return;
  int beg = ptr[n], end = ptr[n+1];
  float id = invd[n];
  float acc[TT/2];
  #pragma unroll
  for (int th = 0; th < TT/2; ++th) acc[th] = 0.f;
  const size_t plane = (size_t)N*FF;
  for (int e = beg; e < end; ++e){
    const float* p = x + (size_t)csr_src[e]*FF + f + (size_t)tp*plane;
    float wv = csr_w[e];
    #pragma unroll
    for (int th = 0; th < TT/2; ++th)
      acc[th] += p[2*th*plane] * wv;
  }
  #pragma unroll
  for (int th = 0; th < TT/2; ++th)
    aggx[(size_t)(2*th+tp)*plane + (size_t)n*FF + f] = acc[th] * id;  // pre-normalized
}

// ================= SAGE linear: emb = agg@Wr + x@Wroot + b ; xr = relu =====
__global__ __launch_bounds__(256) void sage_gemm(
    const float* __restrict__ x, const float* __restrict__ agg,
    const float* __restrict__ Wr, const float* __restrict__ Wroot,
    const float* __restrict__ b,
    float* __restrict__ emb, float* __restrict__ xr, int N){
  __shared__ float sWr[FF*HH], sWroot[FF*HH];
  for (int i = threadIdx.x; i < FF*HH; i += 256){ sWr[i] = Wr[i]; sWroot[i] = Wroot[i]; }
  __syncthreads();
  int idx = blockIdx.x*256 + threadIdx.x;
  int row = idx >> 6, hh = idx & (HH-1);
  if (row >= TT*N) return;
  const float* xv = x   + (size_t)row*FF;
  const float* av = agg + (size_t)row*FF;
  float acc = b[hh];
  #pragma unroll
  for (int k = 0; k < FF; ++k)
    acc += av[k]*sWr[k*HH+hh] + xv[k]*sWroot[k*HH+hh];
  emb[(size_t)row*HH + hh] = acc;
  xr[(size_t)row*HH + hh]  = fmaxf(acc, 0.f);
}

// ========== xr aggregation: t-inner, 12 accumulators per lane ==========
__global__ __launch_bounds__(256) void xr_gather(
    const float* __restrict__ xr, const int* __restrict__ ptr,
    const int* __restrict__ csr_src, const float* __restrict__ csr_w,
    const float* __restrict__ invd, float* __restrict__ xr_agg, int N){
  int wave = threadIdx.x >> 6, lane = threadIdx.x & 63;
  int n = blockIdx.x*4 + wave;
  if (n >= N) return;
  int beg = ptr[n], end = ptr[n+1];
  float id = invd[n];
  float acc[TT];
  #pragma unroll
  for (int t = 0; t < TT; ++t) acc[t] = 0.f;
  const size_t plane = (size_t)N*HH;
  for (int e = beg; e < end; ++e){
    const float* p = xr + (size_t)csr_src[e]*HH + lane;
    float wv = csr_w[e];
    #pragma unroll
    for (int t = 0; t < TT; ++t)
      acc[t] += p[t*plane] * wv;
  }
  #pragma unroll
  for (int t = 0; t < TT; ++t)
    xr_agg[(size_t)t*plane + (size_t)n*HH + lane] = acc[t] * id;  // pre-normalized
}

// ============ fused: h-gather + gates GEMM + LSTM cell, 16 nodes/block ======
// inp = [xr_agg(pre-norm), h_agg*invd, xr, h] ; gates = inp @ [Wr;Wroot] + b
__global__ __launch_bounds__(256) void lstm_step(
    const float* __restrict__ xr_t, const float* __restrict__ xragg_t,
    const float* __restrict__ h_prev, float* __restrict__ h_next,
    float* __restrict__ c, const float* __restrict__ invd,
    const int* __restrict__ ptr, const int* __restrict__ csr_src,
    const float* __restrict__ csr_w,
    const float* __restrict__ Wr, const float* __restrict__ Wroot,
    const float* __restrict__ b,
    float* __restrict__ h2_store, int N){
  __shared__ float lds[16][GG];
  int tid = threadIdx.x, wave = tid >> 6, lane = tid & 63;
  int base = blockIdx.x * 16;

  // ---- Phase A: gather h_agg (unroll-4, 4 loads in flight) + stage inputs ----
  for (int r4 = 0; r4 < 4; ++r4){
    int r = wave*4 + r4;
    int n = base + r;
    if (n < N){
      float id = invd[n];
      int beg = ptr[n], end = ptr[n+1];
      float a0=0.f, a1=0.f, a2=0.f, a3=0.f;
      int e = beg;
      for (; e+4 <= end; e+=4){
        int   s0=csr_src[e],   s1=csr_src[e+1], s2=csr_src[e+2], s3=csr_src[e+3];
        float w0=csr_w[e],     w1=csr_w[e+1],   w2=csr_w[e+2],   w3=csr_w[e+3];
        a0 += h_prev[(size_t)s0*HH+lane]*w0;
        a1 += h_prev[(size_t)s1*HH+lane]*w1;
        a2 += h_prev[(size_t)s2*HH+lane]*w2;
        a3 += h_prev[(size_t)s3*HH+lane]*w3;
      }
      for (; e < end; ++e)
        a0 += h_prev[(size_t)csr_src[e]*HH+lane]*csr_w[e];
      lds[r][ 64+lane] = ((a0+a1)+(a2+a3)) * id;
      lds[r][    lane] = xragg_t[(size_t)n*HH + lane];
      lds[r][128+lane] = xr_t   [(size_t)n*HH + lane];
      lds[r][192+lane] = h_prev [(size_t)n*HH + lane];
    } else {
      lds[r][lane] = lds[r][64+lane] = lds[r][128+lane] = lds[r][192+lane] = 0.f;
    }
  }
  __syncthreads();

  // ---- Phase B: GEMM, 4 rows x 4 cols per thread ----
  int rg = wave;              // rows rg*4 .. rg*4+3
  int j0 = lane * 4;          // cols j0 .. j0+3
  float acc[4][4];
  {
    float4 bv = *(const float4*)&b[j0];
    #pragma unroll
    for (int r = 0; r < 4; ++r){
      acc[r][0]=bv.x; acc[r][1]=bv.y; acc[r][2]=bv.z; acc[r][3]=bv.w;
    }
  }
  #pragma unroll 4
  for (int k = 0; k < 128; k += 4){
    float4 w0 = *(const float4*)&Wr[(size_t)(k+0)*GG + j0];
    float4 w1 = *(const float4*)&Wr[(size_t)(k+1)*GG + j0];
    float4 w2 = *(const float4*)&Wr[(size_t)(k+2)*GG + j0];
    float4 w3 = *(const float4*)&Wr[(size_t)(k+3)*GG + j0];
    #pragma unroll
    for (int r = 0; r < 4; ++r){
      float4 a = *(const float4*)&lds[rg*4+r][k];
      acc[r][0] += a.x*w0.x + a.y*w1.x + a.z*w2.x + a.w*w3.x;
      acc[r][1] += a.x*w0.y + a.y*w1.y + a.z*w2.y + a.w*w3.y;
      acc[r][2] += a.x*w0.z + a.y*w1.z + a.z*w2.z + a.w*w3.z;
      acc[r][3] += a.x*w0.w + a.y*w1.w + a.z*w2.w + a.w*w3.w;
    }
  }
  #pragma unroll 4
  for (int k = 0; k < 128; k += 4){
    float4 w0 = *(const float4*)&Wroot[(size_t)(k+0)*GG + j0];
    float4 w1 = *(const float4*)&Wroot[(size_t)(k+1)*GG + j0];
    float4 w2 = *(const float4*)&Wroot[(size_t)(k+2)*GG + j0];
    float4 w3 = *(const float4*)&Wroot[(size_t)(k+3)*GG + j0];
    #pragma unroll
    for (int r = 0; r < 4; ++r){
      float4 a = *(const float4*)&lds[rg*4+r][128+k];
      acc[r][0] += a.x*w0.x + a.y*w1.x + a.z*w2.x + a.w*w3.x;
      acc[r][1] += a.x*w0.y + a.y*w1.y + a.z*w2.y + a.w*w3.y;
      acc[r][2] += a.x*w0.z + a.y*w1.z + a.z*w2.z + a.w*w3.z;
      acc[r][3] += a.x*w0.w + a.y*w1.w + a.z*w2.w + a.w*w3.w;
    }
  }
  __syncthreads();                      // done reading A-tile
  #pragma unroll
  for (int r = 0; r < 4; ++r){
    float4 g4; g4.x=acc[r][0]; g4.y=acc[r][1]; g4.z=acc[r][2]; g4.w=acc[r][3];
    *(float4*)&lds[rg*4+r][j0] = g4;    // gates
  }
  __syncthreads();

  // ---- Phase C: cell update ----
  int g = wave, hx = lane;
  for (int r = g; r < 16; r += 4){
    int n = base + r;
    if (n >= N) continue;
    float gi = lds[r][hx], gf = lds[r][64+hx], gg2 = lds[r][128+hx], go = lds[r][192+hx];
    float cn = sigmoidf_(gf)*c[(size_t)n*HH+hx] + sigmoidf_(gi)*tanhf(gg2);
    float hn = sigmoidf_(go)*tanhf(cn);
    c[(size_t)n*HH+hx] = cn;
    h_next[(size_t)n*HH+hx] = hn;
    if (h2_store) h2_store[(size_t)n*HH+hx] = hn;
  }
}

// ================= output head =================
__global__ void out_gemm(const float* __restrict__ xr8, const float* __restrict__ h2s,
                         const float* __restrict__ Wout, const float* __restrict__ bout,
                         float* __restrict__ out, int N){
  int idx = blockIdx.x*blockDim.x + threadIdx.x;
  if (idx >= NF*N*OO) return;
  int o = idx & (OO-1);
  int row = idx >> 3;                     // tt*N + n
  const float* xv = xr8 + (size_t)row*HH;
  const float* hv = h2s + (size_t)row*HH;
  float acc = bout[o];
  #pragma unroll
  for (int k = 0; k < HH; ++k)
    acc += xv[k]*Wout[k*OO+o] + hv[k]*Wout[(HH+k)*OO+o];
  out[idx] = acc;
}

__global__ void copyk(const float* __restrict__ s, float* __restrict__ d, int n){
  int i = blockIdx.x*blockDim.x + threadIdx.x;
  if (i < n) d[i] = s[i];
}

extern "C" void kernel_launch(void* const* d_in, const int* in_sizes, int n_in,
                              void* d_out, int out_size, void* d_ws, size_t ws_size,
                              hipStream_t stream){
  const float* x      = (const float*)d_in[0];
  const int*   ei     = (const int*)  d_in[1];
  const float* ew     = (const float*)d_in[2];
  const float* sWr    = (const float*)d_in[3];
  const float* sWroot = (const float*)d_in[4];
  const float* sb     = (const float*)d_in[5];
  const float* l1Wr   = (const float*)d_in[6];
  const float* l1Wroot= (const float*)d_in[7];
  const float* l1b    = (const float*)d_in[8];
  const float* l2Wr   = (const float*)d_in[9];
  const float* l2Wroot= (const float*)d_in[10];
  const float* l2b    = (const float*)d_in[11];
  const float* Wout   = (const float*)d_in[12];
  const float* bout   = (const float*)d_in[13];

  const int E = in_sizes[2];
  const int N = in_sizes[0] / (TT*FF);
  const int* src = ei;
  const int* dst = ei + E;

  float* out0   = (float*)d_out;              // [4,N,8]
  float* c2out  = out0 + (size_t)NF*N*OO;     // [N,64]
  float* embout = c2out + (size_t)N*HH;       // [12,N,64]

  float* w = (float*)d_ws;
  float* xr     = w;  w += (size_t)TT*N*HH;
  float* xr_agg = w;  w += (size_t)TT*N*HH;
  float* agg_x  = xr_agg;                     // alias: dead before xr_agg written
  float* hA     = w;  w += (size_t)N*HH;
  float* hB     = w;  w += (size_t)N*HH;
  float* cbuf   = w;  w += (size_t)N*HH;
  float* h2s    = w;  w += (size_t)NF*N*HH;
  float* invd   = w;  w += N;
  int*   cnt    = (int*)w;  w += N;
  int*   fill   = (int*)w;  w += N;
  int*   ptr    = (int*)w;  w += (N+1);
  int*   csr_src= (int*)w;  w += E;
  float* csr_w  = w;  w += E;

  hipMemsetAsync(cnt,  0, (size_t)N*4, stream);
  hipMemsetAsync(fill, 0, (size_t)N*4, stream);
  hipMemsetAsync(hA,   0, (size_t)N*HH*4, stream);  // h0
  hipMemsetAsync(cbuf, 0, (size_t)N*HH*4, stream);  // c0

  hist_kernel<<<(E+255)/256, 256, 0, stream>>>(dst, cnt, E);
  scan_kernel<<<1, 1024, 0, stream>>>(cnt, ptr, invd, N);
  fill_kernel<<<(E+255)/256, 256, 0, stream>>>(src, dst, ew, ptr, fill, csr_src, csr_w, E);

  sage_gather<<<(N+3)/4, 256, 0, stream>>>(x, ptr, csr_src, csr_w, invd, agg_x, N);
  sage_gemm<<<((size_t)TT*N*HH+255)/256, 256, 0, stream>>>(x, agg_x, sWr, sWroot, sb,
                                                           embout, xr, N);
  xr_gather<<<(N+3)/4, 256, 0, stream>>>(xr, ptr, csr_src, csr_w, invd, xr_agg, N);

  const int stepBlocks = (N+15)/16;
  float* hp = hA; float* hn = hB;
  // LSTM1
  for (int t = 0; t < TT; ++t){
    lstm_step<<<stepBlocks, 256, 0, stream>>>(xr + (size_t)t*N*HH, xr_agg + (size_t)t*N*HH,
                                              hp, hn, cbuf, invd, ptr, csr_src, csr_w,
                                              l1Wr, l1Wroot, l1b, nullptr, N);
    float* tmp = hp; hp = hn; hn = tmp;
  }
  // LSTM2 (continues from h1[-1], c1)
  for (int t = 0; t < TT; ++t){
    float* store = (t >= TT-NF) ? (h2s + (size_t)(t-(TT-NF))*N*HH) : nullptr;
    lstm_step<<<stepBlocks, 256, 0, stream>>>(xr + (size_t)t*N*HH, xr_agg + (size_t)t*N*HH,
                                              hp, hn, cbuf, invd, ptr, csr_src, csr_w,
                                              l2Wr, l2Wroot, l2b, store, N);
    float* tmp = hp; hp = hn; hn = tmp;
  }

  out_gemm<<<((size_t)NF*N*OO+255)/256, 256, 0, stream>>>(xr + (size_t)(TT-NF)*N*HH, h2s,
                                                          Wout, bout, out0, N);
  copyk<<<((size_t)N*HH+255)/256, 256, 0, stream>>>(cbuf, c2out, N*HH);
}